// Round 1
// baseline (146.389 us; speedup 1.0000x reference)
//
#include <hip/hip_runtime.h>
#include <stdint.h>

#define B 8
#define H 192
#define W 192
#define NPIX (B * H * W) /* 294912 */
#define INFF 1e12f

// ---------------------------------------------------------------------------
// K1: column pass. One thread per (b, w) column. Forward + backward saturating
// run-length scans give, for every pixel, the squared distance along the
// column to the nearest False pixel (fg-EDT seed) and nearest True pixel
// (bg-EDT seed), for both the pred mask (sigmoid(x)>0.5 <=> x>0) and the
// target mask (t>0.5). 255 is the "none seen" sentinel (real dists <= 191).
// Outputs 4 squared-distance fields g[4][B][H][W] into workspace.
// ---------------------------------------------------------------------------
__global__ __launch_bounds__(64) void col_pass(
    const float* __restrict__ pred, const float* __restrict__ targ,
    float* __restrict__ g, uint32_t* __restrict__ fwd, float* __restrict__ out) {
  int t = blockIdx.x * blockDim.x + threadIdx.x;
  if (t == 0) *out = 0.0f;  // harness poisons d_out to 0xAA each call
  if (t >= B * W) return;
  int b = t / W, w = t % W;
  const float* pp = pred + b * H * W + w;
  const float* tt = targ + b * H * W + w;
  uint32_t* fw = fwd + b * H * W + w;

  int dFp = 255, dTp = 255, dFt = 255, dTt = 255;
  for (int h = 0; h < H; ++h) {
    float xv = pp[h * W];
    float tv = tt[h * W];
    int mp = xv > 0.0f;
    int mt = tv > 0.5f;
    dFp = mp ? min(dFp + 1, 255) : 0;
    dTp = mp ? 0 : min(dTp + 1, 255);
    dFt = mt ? min(dFt + 1, 255) : 0;
    dTt = mt ? 0 : min(dTt + 1, 255);
    // exactly one of (dF,dT) is zero; store the nonzero one + the mask bit
    uint32_t word = (uint32_t)(mp ? dFp : dTp) | ((uint32_t)mp << 8) |
                    ((uint32_t)(mt ? dFt : dTt) << 16) | ((uint32_t)mt << 24);
    fw[h * W] = word;
  }

  int bFp = 255, bTp = 255, bFt = 255, bTt = 255;
  float* g0 = g + 0 * NPIX + b * H * W + w;  // pred fg-EDT seed
  float* g1 = g + 1 * NPIX + b * H * W + w;  // pred bg-EDT seed
  float* g2 = g + 2 * NPIX + b * H * W + w;  // targ fg-EDT seed
  float* g3 = g + 3 * NPIX + b * H * W + w;  // targ bg-EDT seed
  for (int h = H - 1; h >= 0; --h) {
    uint32_t word = fw[h * W];
    int sp = word & 255, mp = (word >> 8) & 1;
    int st = (word >> 16) & 255, mt = (word >> 24) & 1;
    bFp = mp ? min(bFp + 1, 255) : 0;
    bTp = mp ? 0 : min(bTp + 1, 255);
    bFt = mt ? min(bFt + 1, 255) : 0;
    bTt = mt ? 0 : min(bTt + 1, 255);
    int dF_p = min(mp ? sp : 0, bFp);
    int dT_p = min(mp ? 0 : sp, bTp);
    int dF_t = min(mt ? st : 0, bFt);
    int dT_t = min(mt ? 0 : st, bTt);
    g0[h * W] = (dF_p >= 255) ? INFF : (float)(dF_p * dF_p);
    g1[h * W] = (dT_p >= 255) ? INFF : (float)(dT_p * dT_p);
    g2[h * W] = (dF_t >= 255) ? INFF : (float)(dF_t * dF_t);
    g3[h * W] = (dT_t >= 255) ? INFF : (float)(dT_t * dT_t);
  }
}

// ---------------------------------------------------------------------------
// K2: row pass + fused loss. One block per (b, h) row, one thread per w.
// D2[w] = min_q (w-q)^2 + g_sel[q], g_sel chosen per-pixel by its mask
// (fg pixels need edt(fg), bg pixels need edt(~fg); the other term is 0).
// Then term = (sigmoid(x)-t)^2 * (pd^2+td^2)/(pd+td)^2, block-reduced and
// atomically accumulated (pre-scaled by 1/NPIX) into the scalar output.
// LDS rows padded to 200 floats so the 4 arrays start in different banks.
// ---------------------------------------------------------------------------
__global__ __launch_bounds__(192) void row_pass(
    const float* __restrict__ pred, const float* __restrict__ targ,
    const float* __restrict__ g, float* __restrict__ out) {
  int bh = blockIdx.x;
  int b = bh / H, h = bh % H;
  int w = threadIdx.x;
  __shared__ float sm[4][200];
  __shared__ float wsum[3];
  int base = b * H * W + h * W;
#pragma unroll
  for (int a = 0; a < 4; ++a) sm[a][w] = g[a * NPIX + base + w];
  __syncthreads();

  float xv = pred[base + w];
  float tv = targ[base + w];
  const float* gp = (xv > 0.0f) ? sm[0] : sm[1];
  const float* gt = (tv > 0.5f) ? sm[2] : sm[3];
  float f2p = INFF, f2t = INFF;
#pragma unroll 4
  for (int q = 0; q < W; ++q) {
    float c = (float)((w - q) * (w - q));
    f2p = fminf(f2p, c + gp[q]);
    f2t = fminf(f2t, c + gt[q]);
  }

  float p = 1.0f / (1.0f + __expf(-xv));
  float e = p - tv;
  float err = e * e;
  float pd = sqrtf(f2p), td = sqrtf(f2t);
  float s = pd + td;
  float term = err * (f2p + f2t) / (s * s);  // f2 >= 1 always: no 0/0

  for (int off = 32; off > 0; off >>= 1) term += __shfl_down(term, off, 64);
  if ((w & 63) == 0) wsum[w >> 6] = term;
  __syncthreads();
  if (w == 0)
    atomicAdd(out, (wsum[0] + wsum[1] + wsum[2]) * (1.0f / (float)NPIX));
}

extern "C" void kernel_launch(void* const* d_in, const int* in_sizes, int n_in,
                              void* d_out, int out_size, void* d_ws, size_t ws_size,
                              hipStream_t stream) {
  const float* pred = (const float*)d_in[0];
  const float* targ = (const float*)d_in[1];
  float* out = (float*)d_out;
  float* g = (float*)d_ws;                                          // 4*NPIX floats
  uint32_t* fwd = (uint32_t*)((char*)d_ws + (size_t)4 * NPIX * 4);  // NPIX u32

  col_pass<<<(B * W + 63) / 64, 64, 0, stream>>>(pred, targ, g, fwd, out);
  row_pass<<<B * H, 192, 0, stream>>>(pred, targ, g, out);
}

// Round 2
// 104.733 us; speedup vs baseline: 1.3977x; 1.3977x over previous
//
#include <hip/hip_runtime.h>
#include <stdint.h>

#define B 8
#define H 192
#define W 192
#define NPIX (B * H * W) /* 294912 */
#define INFF 1e12f

// ---------------------------------------------------------------------------
// K1: column pass. One thread per (b, w) column. Forward + backward saturating
// run-length scans give per-pixel the COLUMN distance to the nearest False
// (fg seed) / nearest True (bg seed) pixel for both masks. Forward state is
// staged in LDS (48 KB/block, own-thread slots only -> no sync, 2-way bank
// aliasing = free). Output: 4 distances packed u8 in one u32 per pixel
// (255 = "none in column" sentinel; true distances <= 191).
// Loads across h are independent -> unroll 8 gives 16 outstanding loads and
// hides the ~300-900 cyc global latency that dominated R0 (70 us @ 0.24% occ).
// ---------------------------------------------------------------------------
__global__ __launch_bounds__(64) void col_pass(
    const float* __restrict__ pred, const float* __restrict__ targ,
    uint32_t* __restrict__ g32, float* __restrict__ out) {
  __shared__ uint32_t st[H * 64];
  int tid = threadIdx.x;
  int t = blockIdx.x * 64 + tid;  // grid exactly covers B*W = 1536
  if (t == 0) *out = 0.0f;        // harness poisons d_out each call
  int b = t / W, w = t % W;
  const float* pp = pred + b * H * W + w;
  const float* tt = targ + b * H * W + w;

  int dFp = 255, dTp = 255, dFt = 255, dTt = 255;
#pragma unroll 8
  for (int h = 0; h < H; ++h) {
    float xv = pp[h * W];
    float tv = tt[h * W];
    int mp = xv > 0.0f;   // sigmoid(x) > 0.5  <=>  x > 0
    int mt = tv > 0.5f;
    dFp = mp ? min(dFp + 1, 255) : 0;
    dTp = mp ? 0 : min(dTp + 1, 255);
    dFt = mt ? min(dFt + 1, 255) : 0;
    dTt = mt ? 0 : min(dTt + 1, 255);
    // exactly one of (dF,dT) is zero; store the nonzero one + the mask bit
    uint32_t word = (uint32_t)(mp ? dFp : dTp) | ((uint32_t)mp << 8) |
                    ((uint32_t)(mt ? dFt : dTt) << 16) | ((uint32_t)mt << 24);
    st[h * 64 + tid] = word;
  }

  uint32_t* go = g32 + b * H * W + w;
  int bFp = 255, bTp = 255, bFt = 255, bTt = 255;
#pragma unroll 4
  for (int h = H - 1; h >= 0; --h) {
    uint32_t word = st[h * 64 + tid];
    int sp = word & 255, mp = (word >> 8) & 1;
    int sv = (word >> 16) & 255, mt = (word >> 24) & 1;
    bFp = mp ? min(bFp + 1, 255) : 0;
    bTp = mp ? 0 : min(bTp + 1, 255);
    bFt = mt ? min(bFt + 1, 255) : 0;
    bTt = mt ? 0 : min(bTt + 1, 255);
    int dF_p = min(mp ? sp : 0, bFp);
    int dT_p = min(mp ? 0 : sp, bTp);
    int dF_t = min(mt ? sv : 0, bFt);
    int dT_t = min(mt ? 0 : sv, bTt);
    go[h * W] = (uint32_t)dF_p | ((uint32_t)dT_p << 8) |
                ((uint32_t)dF_t << 16) | ((uint32_t)dT_t << 24);
  }
}

// ---------------------------------------------------------------------------
// K2: row pass + fused loss. One block per (b, h) row, one thread per w.
// D2[w] = min_q (w-q)^2 + d[q]^2 over the per-pixel-selected field. Since
// (w-q)^2 >= r^2 once |w-q| >= r, scanning outward from q=w terminates as
// soon as r^2 >= current best -- exact, and ~3-10 trips for random masks
// instead of 192. Then the fused sigmoid/error/ratio term, wave-shuffle +
// LDS block reduction, one pre-scaled atomicAdd per block.
// ---------------------------------------------------------------------------
__global__ __launch_bounds__(192) void row_pass(
    const float* __restrict__ pred, const float* __restrict__ targ,
    const uint32_t* __restrict__ g32, float* __restrict__ out) {
  int bh = blockIdx.x;
  int b = bh / H, h = bh % H;
  int w = threadIdx.x;
  __shared__ uint32_t sm[W];
  __shared__ float wsum[3];
  int base = b * H * W + h * W;
  uint32_t own = g32[base + w];
  sm[w] = own;
  float xv = pred[base + w];
  float tv = targ[base + w];
  __syncthreads();

  int shp = (xv > 0.0f) ? 0 : 8;    // fg pixel needs fg-EDT field, else bg
  int sht = (tv > 0.5f) ? 16 : 24;
  int dp = (own >> shp) & 255;
  int dt = (own >> sht) & 255;
  float bp = (dp == 255) ? INFF : (float)(dp * dp);
  float bt = (dt == 255) ? INFF : (float)(dt * dt);
  for (int r = 1; r < W; ++r) {
    float rr = (float)(r * r);
    if (rr >= fmaxf(bp, bt)) break;  // no farther q can improve either min
    int ql = w - r, qr = w + r;
    if (ql >= 0) {
      uint32_t v = sm[ql];
      int a = (v >> shp) & 255, c = (v >> sht) & 255;
      bp = fminf(bp, (a == 255) ? INFF : rr + (float)(a * a));
      bt = fminf(bt, (c == 255) ? INFF : rr + (float)(c * c));
    }
    if (qr < W) {
      uint32_t v = sm[qr];
      int a = (v >> shp) & 255, c = (v >> sht) & 255;
      bp = fminf(bp, (a == 255) ? INFF : rr + (float)(a * a));
      bt = fminf(bt, (c == 255) ? INFF : rr + (float)(c * c));
    }
  }

  float p = 1.0f / (1.0f + __expf(-xv));
  float e = p - tv;
  float err = e * e;
  float pd = sqrtf(bp), td = sqrtf(bt);
  float s = pd + td;
  float term = err * (bp + bt) / (s * s);  // bp,bt >= 1 always: no 0/0

  for (int off = 32; off > 0; off >>= 1) term += __shfl_down(term, off, 64);
  if ((w & 63) == 0) wsum[w >> 6] = term;
  __syncthreads();
  if (w == 0)
    atomicAdd(out, (wsum[0] + wsum[1] + wsum[2]) * (1.0f / (float)NPIX));
}

extern "C" void kernel_launch(void* const* d_in, const int* in_sizes, int n_in,
                              void* d_out, int out_size, void* d_ws, size_t ws_size,
                              hipStream_t stream) {
  const float* pred = (const float*)d_in[0];
  const float* targ = (const float*)d_in[1];
  float* out = (float*)d_out;
  uint32_t* g32 = (uint32_t*)d_ws;  // NPIX packed u32 (4 x u8 distances)

  col_pass<<<(B * W) / 64, 64, 0, stream>>>(pred, targ, g32, out);
  row_pass<<<B * H, 192, 0, stream>>>(pred, targ, g32, out);
}

// Round 4
// 66.926 us; speedup vs baseline: 2.1873x; 1.5649x over previous
//
#include <hip/hip_runtime.h>
#include <stdint.h>

#define B 8
#define H 192
#define W 192
#define NPIX (B * H * W) /* 294912 */
#define NROWS (B * H)    /* 1536 */
#define INFF 1e12f

// ---------------------------------------------------------------------------
// Distance (clamped to 255) from position h to the nearest set bit in a
// 192-bit column bitset (s2:s1:s0), inclusive of h. H = 192 = exactly 3 u64
// words, so there are no slack bits. Uses __builtin_clzll/ctzll (ROCm's
// __ffsll/__clzll overloads are ambiguous for uint64_t); only called on
// guarded non-zero values.
// ---------------------------------------------------------------------------
__device__ __forceinline__ int hi_pos(uint64_t w0, uint64_t w1, uint64_t w2) {
  if (w2) return 191 - __builtin_clzll(w2);
  if (w1) return 127 - __builtin_clzll(w1);
  if (w0) return 63 - __builtin_clzll(w0);
  return -255;  // none below -> distance >= 255
}
__device__ __forceinline__ int lo_pos(uint64_t w0, uint64_t w1, uint64_t w2) {
  if (w0) return __builtin_ctzll(w0);
  if (w1) return 64 + __builtin_ctzll(w1);
  if (w2) return 128 + __builtin_ctzll(w2);
  return 447;  // none above -> distance >= 255
}
__device__ __forceinline__ int nearest_dist(uint64_t s0, uint64_t s1,
                                            uint64_t s2, int h) {
  int k = h >> 6, r = h & 63;
  uint64_t keepL = (2ull << r) - 1;  // bits 0..r (r=63 -> all ones)
  uint64_t b0 = s0, b1 = s1, b2 = s2;
  if (k == 0) { b0 &= keepL; b1 = 0; b2 = 0; }
  else if (k == 1) { b1 &= keepL; b2 = 0; }
  else { b2 &= keepL; }
  int dbelow = h - hi_pos(b0, b1, b2);
  uint64_t keepU = (~0ull) << r;  // bits r..63
  uint64_t a0 = s0, a1 = s1, a2 = s2;
  if (k == 0) { a0 &= keepU; }
  else if (k == 1) { a0 = 0; a1 &= keepU; }
  else { a0 = 0; a1 = 0; a2 &= keepU; }
  int dabove = lo_pos(a0, a1, a2) - h;
  return min(min(dbelow, dabove), 255);
}

// ---------------------------------------------------------------------------
// K1: column pass, fully parallel. One block per (b, w) column, one thread
// per h. Three wave64 ballots build the 192-bit column mask for pred
// (sigmoid(x)>0.5 <=> x>0) and target (t>0.5); each pixel extracts its four
// column distances (nearest False / nearest True, both masks) with bit scans.
// Output: 4 x u8 packed per pixel (255 = none-in-column sentinel -> INF).
// Replaces the R2 serial 192-step scan (24 blocks, latency-bound ~30 us).
// ---------------------------------------------------------------------------
__global__ __launch_bounds__(192) void col_pass(
    const float* __restrict__ pred, const float* __restrict__ targ,
    uint32_t* __restrict__ g32) {
  int bw = blockIdx.x;  // 0..B*W
  int b = bw / W, w = bw % W;
  int h = threadIdx.x;
  __shared__ uint64_t mP[3], mT[3];
  int idx = b * H * W + h * W + w;
  float xv = pred[idx];
  float tv = targ[idx];
  uint64_t bp = __ballot(xv > 0.0f);
  uint64_t bt = __ballot(tv > 0.5f);
  if ((h & 63) == 0) { mP[h >> 6] = bp; mT[h >> 6] = bt; }
  __syncthreads();
  uint64_t p0 = mP[0], p1 = mP[1], p2 = mP[2];
  uint64_t t0 = mT[0], t1 = mT[1], t2 = mT[2];
  int dFp = nearest_dist(~p0, ~p1, ~p2, h);  // nearest False (pred mask)
  int dTp = nearest_dist(p0, p1, p2, h);     // nearest True  (pred mask)
  int dFt = nearest_dist(~t0, ~t1, ~t2, h);
  int dTt = nearest_dist(t0, t1, t2, h);
  g32[idx] = (uint32_t)dFp | ((uint32_t)dTp << 8) | ((uint32_t)dFt << 16) |
             ((uint32_t)dTt << 24);
}

// ---------------------------------------------------------------------------
// K2: row pass + fused loss. One block per (b, h) row, one thread per w.
// D2[w] = min_q (w-q)^2 + d[q]^2 over the per-pixel-selected column field;
// outward scan from q=w early-terminates when r^2 >= best (exact). Fused
// sigmoid/error/ratio term, block reduction, ONE partial-sum store per block
// (no same-address atomics -> no cross-XCD serialization).
// ---------------------------------------------------------------------------
__global__ __launch_bounds__(192) void row_pass(
    const float* __restrict__ pred, const float* __restrict__ targ,
    const uint32_t* __restrict__ g32, float* __restrict__ partial) {
  int bh = blockIdx.x;
  int b = bh / H, h = bh % H;
  int w = threadIdx.x;
  __shared__ uint32_t sm[W];
  __shared__ float wsum[3];
  int base = b * H * W + h * W;
  uint32_t own = g32[base + w];
  sm[w] = own;
  float xv = pred[base + w];
  float tv = targ[base + w];
  __syncthreads();

  int shp = (xv > 0.0f) ? 0 : 8;   // fg pixel needs fg-EDT field, else bg
  int sht = (tv > 0.5f) ? 16 : 24;
  int dp = (own >> shp) & 255;
  int dt = (own >> sht) & 255;
  float bp = (dp == 255) ? INFF : (float)(dp * dp);
  float bt = (dt == 255) ? INFF : (float)(dt * dt);
  for (int r = 1; r < W; ++r) {
    float rr = (float)(r * r);
    if (rr >= fmaxf(bp, bt)) break;  // farther q can't improve either min
    int ql = w - r, qr = w + r;
    if (ql >= 0) {
      uint32_t v = sm[ql];
      int a = (v >> shp) & 255, c = (v >> sht) & 255;
      bp = fminf(bp, (a == 255) ? INFF : rr + (float)(a * a));
      bt = fminf(bt, (c == 255) ? INFF : rr + (float)(c * c));
    }
    if (qr < W) {
      uint32_t v = sm[qr];
      int a = (v >> shp) & 255, c = (v >> sht) & 255;
      bp = fminf(bp, (a == 255) ? INFF : rr + (float)(a * a));
      bt = fminf(bt, (c == 255) ? INFF : rr + (float)(c * c));
    }
  }

  float p = 1.0f / (1.0f + __expf(-xv));
  float e = p - tv;
  float err = e * e;
  float pd = sqrtf(bp), td = sqrtf(bt);
  float s = pd + td;
  float term = err * (bp + bt) / (s * s);  // bp,bt >= 1 always: no 0/0

  for (int off = 32; off > 0; off >>= 1) term += __shfl_down(term, off, 64);
  if ((w & 63) == 0) wsum[w >> 6] = term;
  __syncthreads();
  if (w == 0) partial[bh] = wsum[0] + wsum[1] + wsum[2];
}

// ---------------------------------------------------------------------------
// K3: final reduce of 1536 row partials -> mean. Plain store to d_out
// (overwrites the harness poison; no init kernel needed).
// ---------------------------------------------------------------------------
__global__ __launch_bounds__(256) void reduce_pass(
    const float* __restrict__ partial, float* __restrict__ out) {
  int t = threadIdx.x;
  float s = 0.0f;
#pragma unroll
  for (int i = t; i < NROWS; i += 256) s += partial[i];
  for (int off = 32; off > 0; off >>= 1) s += __shfl_down(s, off, 64);
  __shared__ float ws[4];
  if ((t & 63) == 0) ws[t >> 6] = s;
  __syncthreads();
  if (t == 0) out[0] = (ws[0] + ws[1] + ws[2] + ws[3]) * (1.0f / (float)NPIX);
}

extern "C" void kernel_launch(void* const* d_in, const int* in_sizes, int n_in,
                              void* d_out, int out_size, void* d_ws, size_t ws_size,
                              hipStream_t stream) {
  const float* pred = (const float*)d_in[0];
  const float* targ = (const float*)d_in[1];
  float* out = (float*)d_out;
  uint32_t* g32 = (uint32_t*)d_ws;                              // NPIX u32
  float* partial = (float*)((char*)d_ws + (size_t)NPIX * 4);    // NROWS f32

  col_pass<<<B * W, 192, 0, stream>>>(pred, targ, g32);
  row_pass<<<NROWS, 192, 0, stream>>>(pred, targ, g32, partial);
  reduce_pass<<<1, 256, 0, stream>>>(partial, out);
}